// Round 3
// baseline (208.484 us; speedup 1.0000x reference)
//
#include <hip/hip_runtime.h>
#include <cstdint>
#include <math.h>

#define B_   8
#define S_   1024
#define D_   1024
#define NH_  16
#define NKV_ 8
#define HD_  64
#define M_   (B_*S_)   // 8192 tokens

using bf16   = __bf16;
using bf16x4 = __attribute__((ext_vector_type(4))) __bf16;
using bf16x8 = __attribute__((ext_vector_type(8))) __bf16;
using f32x4  = __attribute__((ext_vector_type(4))) float;

// ---------------- async global->LDS, width 16 (m97 idiom) ----------------
__device__ __forceinline__ void gll16(const bf16* g, const bf16* l) {
    __builtin_amdgcn_global_load_lds(
        (const __attribute__((address_space(1))) unsigned int*)(uintptr_t)g,
        (__attribute__((address_space(3))) unsigned int*)(uintptr_t)l,
        16, 0, 0);
}

__device__ __forceinline__ void vm_wait0()  { asm volatile("s_waitcnt vmcnt(0)"  ::: "memory"); }
__device__ __forceinline__ void vm_wait6()  { asm volatile("s_waitcnt vmcnt(6)"  ::: "memory"); }
__device__ __forceinline__ void vm_wait12() { asm volatile("s_waitcnt vmcnt(12)" ::: "memory"); }
__device__ __forceinline__ void bar()       { __builtin_amdgcn_s_barrier(); asm volatile("" ::: "memory"); }

// ---------------- fused prep1: f32->bf16 cvt (blocks 0..8191) + weight transposes ----------------
__global__ void k_prep1(const float* __restrict__ x,
                        const float* __restrict__ wq, const float* __restrict__ wk,
                        const float* __restrict__ wv, const float* __restrict__ wo,
                        bf16* __restrict__ xb, bf16* __restrict__ wqkvT, bf16* __restrict__ woT) {
    __shared__ float tile[64 * 65];
    int bid = blockIdx.x;
    int t = threadIdx.x;
    if (bid < 8192) {                       // cvt: 8192*256 threads cover M_*D_/4 exactly
        int i = bid * 256 + t;
        float4 v = ((const float4*)x)[i];
        bf16x4 o = { (bf16)v.x, (bf16)v.y, (bf16)v.z, (bf16)v.w };
        ((bf16x4*)xb)[i] = o;
        return;
    }
    int b2 = bid - 8192;                    // 0..767 transpose tiles
    int bx = b2 % 48, by = b2 / 48;
    const int R = 1024;
    const float* in; bf16* out; int C, xo;
    if (bx < 16)      { in = wq; out = wqkvT;               C = 1024; xo = bx; }
    else if (bx < 24) { in = wk; out = wqkvT + 1024 * 1024; C = 512;  xo = bx - 16; }
    else if (bx < 32) { in = wv; out = wqkvT + 1536 * 1024; C = 512;  xo = bx - 24; }
    else              { in = wo; out = woT;                 C = 1024; xo = bx - 32; }
    int r0 = by * 64, c0 = xo * 64;
    #pragma unroll
    for (int it = 0; it < 16; ++it) {
        int idx = it * 256 + t;
        int r = idx >> 6, c = idx & 63;
        tile[r * 65 + c] = in[(size_t)(r0 + r) * C + c0 + c];
    }
    __syncthreads();
    #pragma unroll
    for (int it = 0; it < 16; ++it) {
        int idx = it * 256 + t;
        int c = idx >> 6, r = idx & 63;
        out[(size_t)(c0 + c) * R + r0 + r] = (bf16)tile[r * 65 + c];
    }
}

// ---------------- 256x128 GEMM, triple-buffered LDS, counted vmcnt (never drains) ----------------
// Tile 256x128, BK=64, 8 waves (4M x 2N), per-wave 64x64 output (acc 64 VGPR).
// 3 LDS buffers (144 KB): tile T reads buf T%3 while tiles T+1, T+2 are in flight.
// Per tile: stage(T+2) -> vmcnt(12) [T's loads issued 2 tiles (~4000cy) ago: wait is
// free, 12 loads stay queued -> vmem pipe never empties] -> bar -> ds+MFMA (compiler
// schedules; waves skew so LDS and MFMA pipes overlap) -> bar. Two bars/tile.
// This is m218's counted-vs-drain0 lever (+38-73%), which round 2's schedule lacked
// (its in-flight depth never exceeded one tile, so every boundary drained to 0).
template <typename OutT>
__global__ __launch_bounds__(512, 2) void k_gemm256(const bf16* __restrict__ A,
                                                    const bf16* __restrict__ Bt,
                                                    OutT* __restrict__ C, int M, int N, int K) {
    __shared__ __align__(16) bf16 aL3[3 * 256 * 64];   // 96 KB
    __shared__ __align__(16) bf16 bL3[3 * 128 * 64];   // 48 KB
    const int t    = threadIdx.x;
    const int lane = t & 63;
    const int w    = t >> 6;
    const int quad = lane >> 4;
    const int l16  = lane & 15;
    const int wr   = w >> 1;               // 0..3  (M)
    const int wc   = w & 1;                // 0..1  (N)

    // XCD swizzle: bid%8 == XCD -> contiguous grid chunk per XCD (nwg % 8 == 0)
    int bid = blockIdx.y * gridDim.x + blockIdx.x;
    int cpx = (gridDim.x * gridDim.y) >> 3;
    int sw  = (bid & 7) * cpx + (bid >> 3);
    int bx  = sw % gridDim.x, by = sw / gridDim.x;
    const int m0 = by * 256;
    const int n0 = bx * 128;

    f32x4 acc[4][4] = {};

    auto stage = [&](int kb, int sbuf) {   // 6 gll16/thread: A 4 + B 2
        const int k0 = kb << 6;
        #pragma unroll
        for (int it = 0; it < 4; ++it) {   // A: 256 rows x 8 chunks = 2048 / 512thr
            int ci = it * 512 + t;
            int r = ci >> 3, c = ci & 7;
            int cg = c ^ (r & 7);          // slot c of row r holds global chunk c^(r&7)
            gll16(A + (size_t)(m0 + r) * K + k0 + cg * 8, aL3 + sbuf * (256 * 64) + ci * 8);
        }
        #pragma unroll
        for (int it = 0; it < 2; ++it) {   // B: 128 rows x 8 chunks = 1024 / 512thr
            int ci = it * 512 + t;
            int r = ci >> 3, c = ci & 7;
            int cg = c ^ (r & 7);
            gll16(Bt + (size_t)(n0 + r) * K + k0 + cg * 8, bL3 + sbuf * (128 * 64) + ci * 8);
        }
    };

    const int NT = K >> 6;                 // 16 for K=1024

    auto doTile = [&](int T, int CUR, int STG) {
        if (T + 2 < NT) { stage(T + 2, STG); vm_wait12(); }
        else if (T + 1 < NT) vm_wait6();
        else vm_wait0();
        bar();                                      // publish tile T's LDS to all waves
        const bf16* aL = aL3 + CUR * (256 * 64);
        const bf16* bL = bL3 + CUR * (128 * 64);
        #pragma unroll
        for (int kk = 0; kk < 2; ++kk) {
            bf16x8 af[4], bfr[4];
            #pragma unroll
            for (int mi = 0; mi < 4; ++mi) {
                int row = wr * 64 + mi * 16 + l16;
                int ch  = (kk * 4 + quad) ^ (row & 7);
                af[mi] = *(const bf16x8*)&aL[row * 64 + ch * 8];
            }
            #pragma unroll
            for (int ni = 0; ni < 4; ++ni) {
                int row = wc * 64 + ni * 16 + l16;
                int ch  = (kk * 4 + quad) ^ (row & 7);
                bfr[ni] = *(const bf16x8*)&bL[row * 64 + ch * 8];
            }
            __builtin_amdgcn_s_setprio(1);
            #pragma unroll
            for (int mi = 0; mi < 4; ++mi)
                #pragma unroll
                for (int ni = 0; ni < 4; ++ni)
                    acc[mi][ni] = __builtin_amdgcn_mfma_f32_16x16x32_bf16(af[mi], bfr[ni], acc[mi][ni], 0, 0, 0);
            __builtin_amdgcn_s_setprio(0);
        }
        bar();                                      // all reads of CUR done before it is restaged
    };

    stage(0, 0);
    stage(1, 1);
    for (int T = 0; T < NT; T += 3) {      // literal buffer indices via x3 unroll
        doTile(T, 0, 2);
        if (T + 1 < NT) doTile(T + 1, 1, 0);
        if (T + 2 < NT) doTile(T + 2, 2, 1);
    }

    #pragma unroll
    for (int mi = 0; mi < 4; ++mi)
        #pragma unroll
        for (int ni = 0; ni < 4; ++ni)
            #pragma unroll
            for (int r = 0; r < 4; ++r) {
                int row = m0 + wr * 64 + mi * 16 + quad * 4 + r;    // C/D: row = quad*4+reg
                int col = n0 + wc * 64 + ni * 16 + l16;             //      col = lane&15
                C[(size_t)row * N + col] = (OutT)acc[mi][ni][r];
            }
}

// ---------------- fused prep2: RoPE scatter (blocks 0..8191) + V transpose ----------------
__global__ void k_prep2(const bf16* __restrict__ qkv, const float* __restrict__ cosg,
                        const float* __restrict__ sing, bf16* __restrict__ qd,
                        bf16* __restrict__ kd, bf16* __restrict__ vt) {
    __shared__ __align__(16) bf16 tile[64 * 72];
    int bid = blockIdx.x;
    int t = threadIdx.x;
    if (bid < 8192) {                       // RoPE: 192 active lanes/token
        if (t < 192) {
            int token = bid;
            int b = token >> 10, s = token & 1023;
            int hh = t >> 3, i8 = t & 7;
            float4 c4 = *(const float4*)&cosg[s * 32 + i8 * 4];
            float4 s4 = *(const float4*)&sing[s * 32 + i8 * 4];
            int srcBase, dstBase;
            bf16* dst;
            float sf;
            if (hh < 16) {
                srcBase = token * 2048 + hh * 64;
                dstBase = ((b * NH_ + hh) * S_ + s) * 64;
                dst = qd;
                sf = 0.180336879f;          // 0.125 * log2(e) folded into Q
            } else {
                int h = hh - 16;
                srcBase = token * 2048 + 1024 + h * 64;
                dstBase = ((b * NKV_ + h) * S_ + s) * 64;
                dst = kd;
                sf = 1.0f;
            }
            bf16x8 v = *(const bf16x8*)&qkv[srcBase + i8 * 8];
            const float cc[4] = { c4.x, c4.y, c4.z, c4.w };
            const float ss[4] = { s4.x, s4.y, s4.z, s4.w };
            bf16x8 o;
            #pragma unroll
            for (int j = 0; j < 4; ++j) {
                float e  = (float)v[2 * j];
                float od = (float)v[2 * j + 1];
                o[2 * j]     = (bf16)(sf * (e * cc[j] - od * ss[j]));
                o[2 * j + 1] = (bf16)(sf * (e * ss[j] + od * cc[j]));
            }
            *(bf16x8*)&dst[dstBase + i8 * 8] = o;
        }
        return;
    }
    int b2 = bid - 8192;                    // 0..1023 vtrans tiles
    int st = b2 & 15;
    int h  = (b2 >> 4) & 7;
    int b  = b2 >> 7;
    int s0 = st * 64;
    #pragma unroll
    for (int it = 0; it < 2; ++it) {
        int ci = it * 256 + t;
        int r = ci >> 3, c = ci & 7;           // r = s, c = d-chunk
        *(uint4*)&tile[r * 72 + c * 8] =
            *(const uint4*)&qkv[(size_t)(b * S_ + s0 + r) * 2048 + 1536 + h * 64 + c * 8];
    }
    __syncthreads();
    #pragma unroll
    for (int it = 0; it < 2; ++it) {
        int ci = it * 256 + t;
        int d = ci >> 3, sc = ci & 7;
        int g = sc >> 2, q4 = sc & 3;          // internal chunk -> (32-group, quad)
        bf16x8 v;
        #pragma unroll
        for (int j = 0; j < 8; ++j) {
            int s_ext = g * 32 + q4 * 4 + (j & 3) + 16 * (j >> 2);
            v[j] = tile[s_ext * 72 + d];
        }
        *(bf16x8*)&vt[(size_t)((b * NKV_ + h) * 64 + d) * S_ + s0 + sc * 8] = v;
    }
}

// ---------------- flash attention, per-q-tile blocks, block-causal, no-max softmax ----------------
// Unchanged from round 2 (it improved and left the top-5; limit blast radius).
__global__ __launch_bounds__(256) void k_attn(const bf16* __restrict__ q, const bf16* __restrict__ k,
                                              const bf16* __restrict__ vt, bf16* __restrict__ out) {
    __shared__ __align__(16) bf16 kt[2 * 64 * 64];
    __shared__ __align__(16) bf16 vtt[2 * 64 * 64];
    int bid = blockIdx.x;
    int qt = 15 - (bid >> 7);               // big q-tiles first
    int combo = bid & 127;
    int b = combo >> 4, h = combo & 15;
    int hkv = h >> 1;                       // jnp.repeat: q-head h -> kv head h/2
    int t = threadIdx.x;
    int w = t >> 6, lane = t & 63, quad = lane >> 4, l16 = lane & 15;

    const bf16* qh = q + (size_t)(b * NH_ + h) * S_ * 64;
    int qw = qt * 64 + w * 16;
    const bf16* qb = qh + (size_t)(qw + l16) * 64;
    bf16x8 qf0 = *(const bf16x8*)(qb + quad * 8);
    bf16x8 qf1 = *(const bf16x8*)(qb + 32 + quad * 8);

    const bf16* kg = k  + (size_t)(b * NKV_ + hkv) * S_ * 64;
    const bf16* vg = vt + (size_t)(b * NKV_ + hkv) * 64 * S_;

    const int sr0 = t >> 3;                 // staging row 0..31 (+32 for it=1)
    const int cs  = t & 7;                  // staging swizzled chunk slot

    auto stage = [&](int u, int buf) {
        int k0 = u * 64;
        #pragma unroll
        for (int it = 0; it < 2; ++it) {
            int r  = sr0 + it * 32;
            int cg = cs ^ (r & 7);          // slot cs holds global chunk cs^(r&7)
            int ci = it * 256 + t;
            gll16(kg + (size_t)(k0 + r) * 64 + cg * 8, kt  + buf * 4096 + ci * 8);
            gll16(vg + (size_t)r * S_ + k0 + cg * 8,   vtt + buf * 4096 + ci * 8);
        }
    };

    const bf16 one = (bf16)1.0f;
    const bf16x8 vones = { one, one, one, one, one, one, one, one };

    f32x4 o[4] = {};        // PV C-layout: row q=quad*4+r, col d=dc*16+l16
    f32x4 ol = {};          // ones-column: ol[r] = row-sum of P for q=quad*4+r
    const int klim = ((qw + l16) & ~7) + 8; // block-causal, BLK=8

    auto unit = [&](int u, int buf, bool diag) {
        const bf16* ktb = kt  + buf * 4096;
        const bf16* vtb = vtt + buf * 4096;
        int k0 = u * 64;

        f32x4 sc[4] = {};
        #pragma unroll
        for (int kk = 0; kk < 2; ++kk)
            #pragma unroll
            for (int f = 0; f < 4; ++f) {
                int row = f * 16 + l16;
                int ch  = (kk * 4 + quad) ^ (row & 7);
                bf16x8 af = *(const bf16x8*)&ktb[row * 64 + ch * 8];
                sc[f] = __builtin_amdgcn_mfma_f32_16x16x32_bf16(af, kk ? qf1 : qf0, sc[f], 0, 0, 0);
            }

        // p = exp2(sc) directly (Q pre-scaled); masked -> 0. No running max.
        float p[4][4];
        #pragma unroll
        for (int f = 0; f < 4; ++f)
            #pragma unroll
            for (int r = 0; r < 4; ++r) {
                float pv = __builtin_amdgcn_exp2f(sc[f][r]);
                if (diag && (k0 + f * 16 + quad * 4 + r >= klim)) pv = 0.f;
                p[f][r] = pv;
            }

        // P A-frags: internal k=quad*8+j <-> external k' = kk*32 + quad*4+(j&3)+16*(j>>2)
        bf16x8 pa0, pa1;
        #pragma unroll
        for (int j = 0; j < 4; ++j) {
            pa0[j]     = (bf16)p[0][j];
            pa0[j + 4] = (bf16)p[1][j];
            pa1[j]     = (bf16)p[2][j];
            pa1[j + 4] = (bf16)p[3][j];
        }

        // Row sums via ones-column MFMA
        ol = __builtin_amdgcn_mfma_f32_16x16x32_bf16(pa0, vones, ol, 0, 0, 0);
        ol = __builtin_amdgcn_mfma_f32_16x16x32_bf16(pa1, vones, ol, 0, 0, 0);

        // PV: V pre-permuted in global -> single swizzled b128 per B-frag
        #pragma unroll
        for (int dc = 0; dc < 4; ++dc) {
            int row = dc * 16 + l16;
            #pragma unroll
            for (int kk = 0; kk < 2; ++kk) {
                int ch = (kk * 4 + quad) ^ (row & 7);
                bf16x8 vb = *(const bf16x8*)&vtb[row * 64 + ch * 8];
                o[dc] = __builtin_amdgcn_mfma_f32_16x16x32_bf16(kk ? pa1 : pa0, vb, o[dc], 0, 0, 0);
            }
        }
        vm_wait0();     // next unit's K/V landed (issued before this unit's compute)
        bar();
    };

    const int NU = qt + 1;
    stage(0, 0);
    vm_wait0();
    bar();

    int u = 0;
    for (; u + 2 <= NU; u += 2) {
        stage(u + 1, 1);                    // issue-early under unit u's compute
        unit(u, 0, false);                  // u <= NU-2 here: never diagonal
        if (u + 2 < NU) stage(u + 2, 0);
        unit(u + 1, 1, (u + 1) == NU - 1);
    }
    if (u < NU) unit(u, 0, true);           // odd-NU tail: the diagonal unit

    // epilogue
    #pragma unroll
    for (int r = 0; r < 4; ++r) {
        float invl = 1.0f / ol[r];
        #pragma unroll
        for (int dc = 0; dc < 4; ++dc) {
            int row = qw + quad * 4 + r;
            int col = h * 64 + dc * 16 + l16;
            out[(size_t)(b * S_ + row) * 1024 + col] = (bf16)(o[dc][r] * invl);
        }
    }
}

// ---------------- launch ----------------
extern "C" void kernel_launch(void* const* d_in, const int* in_sizes, int n_in,
                              void* d_out, int out_size, void* d_ws, size_t ws_size,
                              hipStream_t stream) {
    const float* x  = (const float*)d_in[0];
    const float* wq = (const float*)d_in[1];
    const float* wk = (const float*)d_in[2];
    const float* wv = (const float*)d_in[3];
    const float* wo = (const float*)d_in[4];
    const float* fc = (const float*)d_in[5];
    const float* fs = (const float*)d_in[6];
    (void)in_sizes; (void)n_in; (void)out_size; (void)ws_size;

    char* ws = (char*)d_ws;
    bf16* xb    = (bf16*)(ws);                          // 16 MB, reused as q after GEMM1
    bf16* wqkvT = (bf16*)(ws + (16u << 20));            //  4 MB  [2048][1024]
    bf16* woT   = (bf16*)(ws + (20u << 20));            //  2 MB  [1024][1024]
    bf16* qkvb  = (bf16*)(ws + (22u << 20));            // 32 MB  [8192][2048], reused as attn out
    bf16* kb    = (bf16*)(ws + (54u << 20));            //  8 MB  [8][8][1024][64]
    bf16* vtb   = (bf16*)(ws + (62u << 20));            //  8 MB  [8][8][64][1024]  (70 MB total)
    bf16* qb    = xb;
    bf16* attnb = qkvb;

    k_prep1<<<dim3(8960), dim3(256), 0, stream>>>(x, wq, wk, wv, wo, xb, wqkvT, woT);

    // GEMM1: [8192,1024] x [2048,1024]^T -> 256x128 tiles, grid 16x32 = 512 wgs
    k_gemm256<bf16><<<dim3(16, 32), dim3(512), 0, stream>>>(xb, wqkvT, qkvb, M_, 2048, 1024);

    k_prep2<<<dim3(9216), dim3(256), 0, stream>>>(qkvb, fc, fs, qb, kb, vtb);

    // attn: per-q-tile blocks, 2048 wgs, big tiles first
    k_attn<<<dim3(2048), dim3(256), 0, stream>>>(qb, kb, vtb, attnb);

    // GEMM2: [8192,1024] x [1024,1024]^T -> 256x128 tiles, grid 8x32 = 256 wgs (1/CU)
    k_gemm256<float><<<dim3(8, 32), dim3(512), 0, stream>>>(attnb, woT, (float*)d_out, M_, 1024, 1024);
}

// Round 4
// 202.801 us; speedup vs baseline: 1.0280x; 1.0280x over previous
//
#include <hip/hip_runtime.h>
#include <cstdint>
#include <math.h>

#define B_   8
#define S_   1024
#define D_   1024
#define NH_  16
#define NKV_ 8
#define HD_  64
#define M_   (B_*S_)   // 8192 tokens

using bf16   = __bf16;
using bf16x4 = __attribute__((ext_vector_type(4))) __bf16;
using bf16x8 = __attribute__((ext_vector_type(8))) __bf16;
using f32x4  = __attribute__((ext_vector_type(4))) float;

// ---------------- async global->LDS, width 16 (m97 idiom) ----------------
__device__ __forceinline__ void gll16(const bf16* g, const bf16* l) {
    __builtin_amdgcn_global_load_lds(
        (const __attribute__((address_space(1))) unsigned int*)(uintptr_t)g,
        (__attribute__((address_space(3))) unsigned int*)(uintptr_t)l,
        16, 0, 0);
}

__device__ __forceinline__ void vm_wait0()  { asm volatile("s_waitcnt vmcnt(0)"  ::: "memory"); }
__device__ __forceinline__ void vm_wait5()  { asm volatile("s_waitcnt vmcnt(5)"  ::: "memory"); }
__device__ __forceinline__ void vm_wait6()  { asm volatile("s_waitcnt vmcnt(6)"  ::: "memory"); }
__device__ __forceinline__ void bar()       { __builtin_amdgcn_s_barrier(); asm volatile("" ::: "memory"); }

// ---------------- fused prep1: f32->bf16 cvt (blocks 0..8191) + weight transposes ----------------
__global__ void k_prep1(const float* __restrict__ x,
                        const float* __restrict__ wq, const float* __restrict__ wk,
                        const float* __restrict__ wv, const float* __restrict__ wo,
                        bf16* __restrict__ xb, bf16* __restrict__ wqkvT, bf16* __restrict__ woT) {
    __shared__ float tile[64 * 65];
    int bid = blockIdx.x;
    int t = threadIdx.x;
    if (bid < 8192) {                       // cvt: 8192*256 threads cover M_*D_/4 exactly
        int i = bid * 256 + t;
        float4 v = ((const float4*)x)[i];
        bf16x4 o = { (bf16)v.x, (bf16)v.y, (bf16)v.z, (bf16)v.w };
        ((bf16x4*)xb)[i] = o;
        return;
    }
    int b2 = bid - 8192;                    // 0..767 transpose tiles
    int bx = b2 % 48, by = b2 / 48;
    const int R = 1024;
    const float* in; bf16* out; int C, xo;
    if (bx < 16)      { in = wq; out = wqkvT;               C = 1024; xo = bx; }
    else if (bx < 24) { in = wk; out = wqkvT + 1024 * 1024; C = 512;  xo = bx - 16; }
    else if (bx < 32) { in = wv; out = wqkvT + 1536 * 1024; C = 512;  xo = bx - 24; }
    else              { in = wo; out = woT;                 C = 1024; xo = bx - 32; }
    int r0 = by * 64, c0 = xo * 64;
    #pragma unroll
    for (int it = 0; it < 16; ++it) {
        int idx = it * 256 + t;
        int r = idx >> 6, c = idx & 63;
        tile[r * 65 + c] = in[(size_t)(r0 + r) * C + c0 + c];
    }
    __syncthreads();
    #pragma unroll
    for (int it = 0; it < 16; ++it) {
        int idx = it * 256 + t;
        int c = idx >> 6, r = idx & 63;
        out[(size_t)(c0 + c) * R + r0 + r] = (bf16)tile[r * 65 + c];
    }
}

// ---------------- 8-phase GEMM (m201 port): C[M,N] = A[M,K] * Bt[N,K]^T ----------------
// BM=256, BN=NI*64, BK=64, 512 thr (8 waves, 2M x 4N), per-wave 128 x NI*16.
// Phases = C-quadrants (mh,nh) in order (0,0)(0,1)(1,0)(1,1); A-frags held in regs
// across the two nh phases (A LDS-read once per tile). Quarter-granular staging into
// the JUST-FREED regions of the same buffer: A-mh0 quarters free after p0 -> staged
// p1; A-mh1 free after p2 -> staged p3; B rows stored nh-PERMUTED (first half of B
// LDS = all waves' nh0 rows) so B halves align with 64-row stage units: B-nh0 free
// after p2 -> staged p3; B-nh1 free after p3 -> staged next tile's p0.
// ONE counted wait per tile: vmcnt(4+NI/2) at p3 (= next-next tile's in-flight
// loads) -- the vmem queue NEVER drains in steady state (T3+T4, m218's +38-73%
// lever, which rounds 2/3 lacked). setprio(1) around each 16-MFMA cluster (T5).
template <typename OutT, int NI>
__global__ __launch_bounds__(512, 2) void k_gemm8p(const bf16* __restrict__ A,
                                                   const bf16* __restrict__ Bt,
                                                   OutT* __restrict__ C, int M, int N, int K) {
    constexpr int BN = NI * 64;
    __shared__ __align__(16) bf16 aL2[2 * 256 * 64];
    __shared__ __align__(16) bf16 bL2[2 * BN * 64];
    const int t    = threadIdx.x;
    const int lane = t & 63;
    const int w    = t >> 6;
    const int quad = lane >> 4;
    const int l16  = lane & 15;
    const int wr   = w >> 2;               // 0..1  (M)
    const int wc   = w & 3;                // 0..3  (N)

    // XCD swizzle (nwg = 256, divisible by 8)
    int bid = blockIdx.y * gridDim.x + blockIdx.x;
    int cpx = (gridDim.x * gridDim.y) >> 3;
    int sw  = (bid & 7) * cpx + (bid >> 3);
    int bx  = sw % gridDim.x, by = sw / gridDim.x;
    const int m0 = by * 256;
    const int n0 = bx * BN;

    f32x4 acc[8][NI] = {};

    // ---- staging: A quarter-units (64 rows each), B half-units (nh-permuted rows) ----
    auto stageA2 = [&](int kb, int dbuf, int itX, int itY) {
        const int k0 = kb << 6;
        #pragma unroll
        for (int u = 0; u < 2; ++u) {
            int it = u ? itY : itX;
            int ci = it * 512 + t;
            int r = ci >> 3, c = ci & 7;
            int cg = c ^ (r & 7);          // slot c of row r holds global chunk c^(r&7)
            gll16(A + (size_t)(m0 + r) * K + k0 + cg * 8, aL2 + dbuf * (256 * 64) + ci * 8);
        }
    };
    auto stageBh = [&](int kb, int dbuf, int nh) {
        const int k0 = kb << 6;
        #pragma unroll
        for (int j = 0; j < NI / 2; ++j) {
            int it = nh * (NI / 2) + j;
            int ci = it * 512 + t;
            int lr = ci >> 3, cs = ci & 7;
            int cg = cs ^ (lr & 7);
            int idx = lr - nh * (BN / 2);  // position within the nh half
            int wcc = idx / (NI * 8);
            int off = idx % (NI * 8);
            int g   = wcc * (NI * 16) + nh * (NI * 8) + off;   // global B row
            gll16(Bt + (size_t)(n0 + g) * K + k0 + cg * 8, bL2 + dbuf * (BN * 64) + ci * 8);
        }
    };

    // ---- register fragment loads (plain C++ LDS reads: compiler tracks deps) ----
    auto loadA = [&](const bf16* aL, int mh, bf16x8 (&af)[8]) {
        #pragma unroll
        for (int mi = 0; mi < 4; ++mi)
            #pragma unroll
            for (int kk = 0; kk < 2; ++kk) {
                int row = wr * 128 + (mh * 4 + mi) * 16 + l16;
                int ch  = (kk * 4 + quad) ^ (row & 7);
                af[mi * 2 + kk] = *(const bf16x8*)&aL[row * 64 + ch * 8];
            }
    };
    auto loadB = [&](const bf16* bL, int nh, bf16x8 (&bfr)[NI]) {
        #pragma unroll
        for (int j = 0; j < NI / 2; ++j)
            #pragma unroll
            for (int kk = 0; kk < 2; ++kk) {
                int lr = nh * (BN / 2) + wc * (NI * 8) + j * 16 + l16;  // permuted row
                int ch = (kk * 4 + quad) ^ (lr & 7);
                bfr[j * 2 + kk] = *(const bf16x8*)&bL[lr * 64 + ch * 8];
            }
    };
    auto mmac = [&](int mh, int nh, bf16x8 (&af)[8], bf16x8 (&bfr)[NI]) {
        __builtin_amdgcn_s_setprio(1);
        #pragma unroll
        for (int mi = 0; mi < 4; ++mi)
            #pragma unroll
            for (int j = 0; j < NI / 2; ++j)
                #pragma unroll
                for (int kk = 0; kk < 2; ++kk)
                    acc[mh * 4 + mi][nh * (NI / 2) + j] =
                        __builtin_amdgcn_mfma_f32_16x16x32_bf16(af[mi * 2 + kk], bfr[j * 2 + kk],
                                                                acc[mh * 4 + mi][nh * (NI / 2) + j], 0, 0, 0);
        __builtin_amdgcn_s_setprio(0);
    };

    const int NT = K >> 6;                 // 16

    auto tile = [&](int T, int bufc) {
        const bf16* aL = aL2 + bufc * (256 * 64);
        const bf16* bL = bL2 + bufc * (BN * 64);
        bf16x8 af[8], bfr[NI];
        // p0: quadrant (0,0); stage B-nh1 of T+1 into buf^1 (its region freed at T-1.p3)
        loadA(aL, 0, af); loadB(bL, 0, bfr);
        if (T + 1 < NT) stageBh(T + 1, bufc ^ 1, 1);
        bar();
        mmac(0, 0, af, bfr);
        bar();
        // p1: (0,1); stage A quarters mh0 (its 0,2) of T+2 (freed at p0)
        loadB(bL, 1, bfr);
        if (T + 2 < NT) stageA2(T + 2, bufc, 0, 2);
        bar();
        mmac(0, 1, af, bfr);
        bar();
        // p2: (1,0)
        loadA(aL, 1, af); loadB(bL, 0, bfr);
        bar();
        mmac(1, 0, af, bfr);
        bar();
        // p3: (1,1); stage A mh1 quarters (its 1,3) + B-nh0 of T+2 (freed at p2);
        // counted wait: everything older than T+2's 4+NI/2 loads has landed -> tile
        // T+1 fully staged; queue keeps T+2's loads in flight (never drains).
        loadB(bL, 1, bfr);
        if (T + 2 < NT) {
            stageA2(T + 2, bufc, 1, 3);
            stageBh(T + 2, bufc, 0);
            if constexpr (NI == 4) vm_wait6(); else vm_wait5();
        } else {
            vm_wait0();
        }
        bar();
        mmac(1, 1, af, bfr);
        bar();
    };

    // prologue: tile 0 full; tile 1 all but B-nh1 (staged at tile0.p0) -> uniform steady state
    stageA2(0, 0, 0, 2); stageA2(0, 0, 1, 3); stageBh(0, 0, 0); stageBh(0, 0, 1);
    stageA2(1, 1, 0, 2); stageA2(1, 1, 1, 3); stageBh(1, 1, 0);
    if constexpr (NI == 4) vm_wait6(); else vm_wait5();   // tile 0 landed; tile 1 partial in flight
    bar();

    for (int T = 0; T < NT; T += 2) {      // literal buffer index at both call sites
        tile(T, 0);
        tile(T + 1, 1);
    }

    #pragma unroll
    for (int mi = 0; mi < 8; ++mi)
        #pragma unroll
        for (int ni = 0; ni < NI; ++ni)
            #pragma unroll
            for (int r = 0; r < 4; ++r) {
                int row = m0 + wr * 128 + mi * 16 + quad * 4 + r;   // C/D: row = quad*4+reg
                int col = n0 + wc * (NI * 16) + ni * 16 + l16;      //      col = lane&15
                C[(size_t)row * N + col] = (OutT)acc[mi][ni][r];
            }
}

// ---------------- fused prep2: RoPE scatter (blocks 0..8191) + V transpose ----------------
__global__ void k_prep2(const bf16* __restrict__ qkv, const float* __restrict__ cosg,
                        const float* __restrict__ sing, bf16* __restrict__ qd,
                        bf16* __restrict__ kd, bf16* __restrict__ vt) {
    __shared__ __align__(16) bf16 tile[64 * 72];
    int bid = blockIdx.x;
    int t = threadIdx.x;
    if (bid < 8192) {                       // RoPE: 192 active lanes/token
        if (t < 192) {
            int token = bid;
            int b = token >> 10, s = token & 1023;
            int hh = t >> 3, i8 = t & 7;
            float4 c4 = *(const float4*)&cosg[s * 32 + i8 * 4];
            float4 s4 = *(const float4*)&sing[s * 32 + i8 * 4];
            int srcBase, dstBase;
            bf16* dst;
            float sf;
            if (hh < 16) {
                srcBase = token * 2048 + hh * 64;
                dstBase = ((b * NH_ + hh) * S_ + s) * 64;
                dst = qd;
                sf = 0.180336879f;          // 0.125 * log2(e) folded into Q
            } else {
                int h = hh - 16;
                srcBase = token * 2048 + 1024 + h * 64;
                dstBase = ((b * NKV_ + h) * S_ + s) * 64;
                dst = kd;
                sf = 1.0f;
            }
            bf16x8 v = *(const bf16x8*)&qkv[srcBase + i8 * 8];
            const float cc[4] = { c4.x, c4.y, c4.z, c4.w };
            const float ss[4] = { s4.x, s4.y, s4.z, s4.w };
            bf16x8 o;
            #pragma unroll
            for (int j = 0; j < 4; ++j) {
                float e  = (float)v[2 * j];
                float od = (float)v[2 * j + 1];
                o[2 * j]     = (bf16)(sf * (e * cc[j] - od * ss[j]));
                o[2 * j + 1] = (bf16)(sf * (e * ss[j] + od * cc[j]));
            }
            *(bf16x8*)&dst[dstBase + i8 * 8] = o;
        }
        return;
    }
    int b2 = bid - 8192;                    // 0..1023 vtrans tiles
    int st = b2 & 15;
    int h  = (b2 >> 4) & 7;
    int b  = b2 >> 7;
    int s0 = st * 64;
    #pragma unroll
    for (int it = 0; it < 2; ++it) {
        int ci = it * 256 + t;
        int r = ci >> 3, c = ci & 7;           // r = s, c = d-chunk
        *(uint4*)&tile[r * 72 + c * 8] =
            *(const uint4*)&qkv[(size_t)(b * S_ + s0 + r) * 2048 + 1536 + h * 64 + c * 8];
    }
    __syncthreads();
    #pragma unroll
    for (int it = 0; it < 2; ++it) {
        int ci = it * 256 + t;
        int d = ci >> 3, sc = ci & 7;
        int g = sc >> 2, q4 = sc & 3;          // internal chunk -> (32-group, quad)
        bf16x8 v;
        #pragma unroll
        for (int j = 0; j < 8; ++j) {
            int s_ext = g * 32 + q4 * 4 + (j & 3) + 16 * (j >> 2);
            v[j] = tile[s_ext * 72 + d];
        }
        *(bf16x8*)&vt[(size_t)((b * NKV_ + h) * 64 + d) * S_ + s0 + sc * 8] = v;
    }
}

// ---------------- flash attention, per-q-tile blocks, block-causal, no-max softmax ----------------
// Unchanged from round 2 (improved there and left the top-5; limit blast radius).
__global__ __launch_bounds__(256) void k_attn(const bf16* __restrict__ q, const bf16* __restrict__ k,
                                              const bf16* __restrict__ vt, bf16* __restrict__ out) {
    __shared__ __align__(16) bf16 kt[2 * 64 * 64];
    __shared__ __align__(16) bf16 vtt[2 * 64 * 64];
    int bid = blockIdx.x;
    int qt = 15 - (bid >> 7);               // big q-tiles first
    int combo = bid & 127;
    int b = combo >> 4, h = combo & 15;
    int hkv = h >> 1;                       // jnp.repeat: q-head h -> kv head h/2
    int t = threadIdx.x;
    int w = t >> 6, lane = t & 63, quad = lane >> 4, l16 = lane & 15;

    const bf16* qh = q + (size_t)(b * NH_ + h) * S_ * 64;
    int qw = qt * 64 + w * 16;
    const bf16* qb = qh + (size_t)(qw + l16) * 64;
    bf16x8 qf0 = *(const bf16x8*)(qb + quad * 8);
    bf16x8 qf1 = *(const bf16x8*)(qb + 32 + quad * 8);

    const bf16* kg = k  + (size_t)(b * NKV_ + hkv) * S_ * 64;
    const bf16* vg = vt + (size_t)(b * NKV_ + hkv) * 64 * S_;

    const int sr0 = t >> 3;                 // staging row 0..31 (+32 for it=1)
    const int cs  = t & 7;                  // staging swizzled chunk slot

    auto stage = [&](int u, int buf) {
        int k0 = u * 64;
        #pragma unroll
        for (int it = 0; it < 2; ++it) {
            int r  = sr0 + it * 32;
            int cg = cs ^ (r & 7);          // slot cs holds global chunk cs^(r&7)
            int ci = it * 256 + t;
            gll16(kg + (size_t)(k0 + r) * 64 + cg * 8, kt  + buf * 4096 + ci * 8);
            gll16(vg + (size_t)r * S_ + k0 + cg * 8,   vtt + buf * 4096 + ci * 8);
        }
    };

    const bf16 one = (bf16)1.0f;
    const bf16x8 vones = { one, one, one, one, one, one, one, one };

    f32x4 o[4] = {};        // PV C-layout: row q=quad*4+r, col d=dc*16+l16
    f32x4 ol = {};          // ones-column: ol[r] = row-sum of P for q=quad*4+r
    const int klim = ((qw + l16) & ~7) + 8; // block-causal, BLK=8

    auto unit = [&](int u, int buf, bool diag) {
        const bf16* ktb = kt  + buf * 4096;
        const bf16* vtb = vtt + buf * 4096;
        int k0 = u * 64;

        f32x4 sc[4] = {};
        #pragma unroll
        for (int kk = 0; kk < 2; ++kk)
            #pragma unroll
            for (int f = 0; f < 4; ++f) {
                int row = f * 16 + l16;
                int ch  = (kk * 4 + quad) ^ (row & 7);
                bf16x8 af = *(const bf16x8*)&ktb[row * 64 + ch * 8];
                sc[f] = __builtin_amdgcn_mfma_f32_16x16x32_bf16(af, kk ? qf1 : qf0, sc[f], 0, 0, 0);
            }

        // p = exp2(sc) directly (Q pre-scaled); masked -> 0. No running max.
        float p[4][4];
        #pragma unroll
        for (int f = 0; f < 4; ++f)
            #pragma unroll
            for (int r = 0; r < 4; ++r) {
                float pv = __builtin_amdgcn_exp2f(sc[f][r]);
                if (diag && (k0 + f * 16 + quad * 4 + r >= klim)) pv = 0.f;
                p[f][r] = pv;
            }

        // P A-frags: internal k=quad*8+j <-> external k' = kk*32 + quad*4+(j&3)+16*(j>>2)
        bf16x8 pa0, pa1;
        #pragma unroll
        for (int j = 0; j < 4; ++j) {
            pa0[j]     = (bf16)p[0][j];
            pa0[j + 4] = (bf16)p[1][j];
            pa1[j]     = (bf16)p[2][j];
            pa1[j + 4] = (bf16)p[3][j];
        }

        // Row sums via ones-column MFMA
        ol = __builtin_amdgcn_mfma_f32_16x16x32_bf16(pa0, vones, ol, 0, 0, 0);
        ol = __builtin_amdgcn_mfma_f32_16x16x32_bf16(pa1, vones, ol, 0, 0, 0);

        // PV: V pre-permuted in global -> single swizzled b128 per B-frag
        #pragma unroll
        for (int dc = 0; dc < 4; ++dc) {
            int row = dc * 16 + l16;
            #pragma unroll
            for (int kk = 0; kk < 2; ++kk) {
                int ch = (kk * 4 + quad) ^ (row & 7);
                bf16x8 vb = *(const bf16x8*)&vtb[row * 64 + ch * 8];
                o[dc] = __builtin_amdgcn_mfma_f32_16x16x32_bf16(kk ? pa1 : pa0, vb, o[dc], 0, 0, 0);
            }
        }
        vm_wait0();     // next unit's K/V landed (issued before this unit's compute)
        bar();
    };

    const int NU = qt + 1;
    stage(0, 0);
    vm_wait0();
    bar();

    int u = 0;
    for (; u + 2 <= NU; u += 2) {
        stage(u + 1, 1);                    // issue-early under unit u's compute
        unit(u, 0, false);                  // u <= NU-2 here: never diagonal
        if (u + 2 < NU) stage(u + 2, 0);
        unit(u + 1, 1, (u + 1) == NU - 1);
    }
    if (u < NU) unit(u, 0, true);           // odd-NU tail: the diagonal unit

    // epilogue
    #pragma unroll
    for (int r = 0; r < 4; ++r) {
        float invl = 1.0f / ol[r];
        #pragma unroll
        for (int dc = 0; dc < 4; ++dc) {
            int row = qw + quad * 4 + r;
            int col = h * 64 + dc * 16 + l16;
            out[(size_t)(b * S_ + row) * 1024 + col] = (bf16)(o[dc][r] * invl);
        }
    }
}

// ---------------- launch ----------------
extern "C" void kernel_launch(void* const* d_in, const int* in_sizes, int n_in,
                              void* d_out, int out_size, void* d_ws, size_t ws_size,
                              hipStream_t stream) {
    const float* x  = (const float*)d_in[0];
    const float* wq = (const float*)d_in[1];
    const float* wk = (const float*)d_in[2];
    const float* wv = (const float*)d_in[3];
    const float* wo = (const float*)d_in[4];
    const float* fc = (const float*)d_in[5];
    const float* fs = (const float*)d_in[6];
    (void)in_sizes; (void)n_in; (void)out_size; (void)ws_size;

    char* ws = (char*)d_ws;
    bf16* xb    = (bf16*)(ws);                          // 16 MB, reused as q after GEMM1
    bf16* wqkvT = (bf16*)(ws + (16u << 20));            //  4 MB  [2048][1024]
    bf16* woT   = (bf16*)(ws + (20u << 20));            //  2 MB  [1024][1024]
    bf16* qkvb  = (bf16*)(ws + (22u << 20));            // 32 MB  [8192][2048], reused as attn out
    bf16* kb    = (bf16*)(ws + (54u << 20));            //  8 MB  [8][8][1024][64]
    bf16* vtb   = (bf16*)(ws + (62u << 20));            //  8 MB  [8][8][64][1024]  (70 MB total)
    bf16* qb    = xb;
    bf16* attnb = qkvb;

    k_prep1<<<dim3(8960), dim3(256), 0, stream>>>(x, wq, wk, wv, wo, xb, wqkvT, woT);

    // GEMM1: [8192,1024] x [2048,1024]^T -> 256x256 tiles, grid 8x32 = 256 wgs (1/CU)
    k_gemm8p<bf16, 4><<<dim3(8, 32), dim3(512), 0, stream>>>(xb, wqkvT, qkvb, M_, 2048, 1024);

    k_prep2<<<dim3(9216), dim3(256), 0, stream>>>(qkvb, fc, fs, qb, kb, vtb);

    // attn: per-q-tile blocks, 2048 wgs, big tiles first
    k_attn<<<dim3(2048), dim3(256), 0, stream>>>(qb, kb, vtb, attnb);

    // GEMM2: [8192,1024] x [1024,1024]^T -> 256x128 tiles, grid 8x32 = 256 wgs (1/CU)
    k_gemm8p<float, 2><<<dim3(8, 32), dim3(512), 0, stream>>>(attnb, woT, (float*)d_out, M_, 1024, 1024);
}

// Round 5
// 198.838 us; speedup vs baseline: 1.0485x; 1.0199x over previous
//
#include <hip/hip_runtime.h>
#include <cstdint>
#include <math.h>

#define B_   8
#define S_   1024
#define D_   1024
#define NH_  16
#define NKV_ 8
#define HD_  64
#define M_   (B_*S_)   // 8192 tokens

using bf16   = __bf16;
using bf16x4 = __attribute__((ext_vector_type(4))) __bf16;
using bf16x8 = __attribute__((ext_vector_type(8))) __bf16;
using f32x4  = __attribute__((ext_vector_type(4))) float;

// ---------------- async global->LDS, width 16 (m97 idiom) ----------------
__device__ __forceinline__ void gll16(const bf16* g, const bf16* l) {
    __builtin_amdgcn_global_load_lds(
        (const __attribute__((address_space(1))) unsigned int*)(uintptr_t)g,
        (__attribute__((address_space(3))) unsigned int*)(uintptr_t)l,
        16, 0, 0);
}

// Opaque LDS read: the compiler's waitcnt pass cannot see a dependency on
// global_load_lds writes, so it inserts NO vmcnt drains -- ordering is ours
// alone via the manual counted waits below (the m201/HK pattern; rule #18).
__device__ __forceinline__ void dsr128(bf16x8& d, const bf16* p) {
    asm volatile("ds_read_b128 %0, %1" : "=v"(d) : "v"((unsigned)(uintptr_t)p));
}
// rule #18: lgkmcnt(0) then sched_barrier(0) so MFMAs are not hoisted above the wait
__device__ __forceinline__ void lgkm0() {
    asm volatile("s_waitcnt lgkmcnt(0)" ::: "memory");
    __builtin_amdgcn_sched_barrier(0);
}
__device__ __forceinline__ void vm_wait0()  { asm volatile("s_waitcnt vmcnt(0)"  ::: "memory"); }
__device__ __forceinline__ void vm_wait4()  { asm volatile("s_waitcnt vmcnt(4)"  ::: "memory"); }
__device__ __forceinline__ void vm_wait5()  { asm volatile("s_waitcnt vmcnt(5)"  ::: "memory"); }
__device__ __forceinline__ void vm_wait6()  { asm volatile("s_waitcnt vmcnt(6)"  ::: "memory"); }
__device__ __forceinline__ void bar()       { __builtin_amdgcn_s_barrier(); asm volatile("" ::: "memory"); }

// ---------------- fused prep1: f32->bf16 cvt (blocks 0..8191) + weight transposes ----------------
__global__ void k_prep1(const float* __restrict__ x,
                        const float* __restrict__ wq, const float* __restrict__ wk,
                        const float* __restrict__ wv, const float* __restrict__ wo,
                        bf16* __restrict__ xb, bf16* __restrict__ wqkvT, bf16* __restrict__ woT) {
    __shared__ float tile[64 * 65];
    int bid = blockIdx.x;
    int t = threadIdx.x;
    if (bid < 8192) {                       // cvt: 8192*256 threads cover M_*D_/4 exactly
        int i = bid * 256 + t;
        float4 v = ((const float4*)x)[i];
        bf16x4 o = { (bf16)v.x, (bf16)v.y, (bf16)v.z, (bf16)v.w };
        ((bf16x4*)xb)[i] = o;
        return;
    }
    int b2 = bid - 8192;                    // 0..767 transpose tiles
    int bx = b2 % 48, by = b2 / 48;
    const int R = 1024;
    const float* in; bf16* out; int C, xo;
    if (bx < 16)      { in = wq; out = wqkvT;               C = 1024; xo = bx; }
    else if (bx < 24) { in = wk; out = wqkvT + 1024 * 1024; C = 512;  xo = bx - 16; }
    else if (bx < 32) { in = wv; out = wqkvT + 1536 * 1024; C = 512;  xo = bx - 24; }
    else              { in = wo; out = woT;                 C = 1024; xo = bx - 32; }
    int r0 = by * 64, c0 = xo * 64;
    #pragma unroll
    for (int it = 0; it < 16; ++it) {
        int idx = it * 256 + t;
        int r = idx >> 6, c = idx & 63;
        tile[r * 65 + c] = in[(size_t)(r0 + r) * C + c0 + c];
    }
    __syncthreads();
    #pragma unroll
    for (int it = 0; it < 16; ++it) {
        int idx = it * 256 + t;
        int c = idx >> 6, r = idx & 63;
        out[(size_t)(c0 + c) * R + r0 + r] = (bf16)tile[r * 65 + c];
    }
}

// ---------------- 8-phase GEMM, asm ds_read edition ----------------
// Geometry/addressing identical to round 4 (verified): BM=256, BN=NI*64, BK=64,
// 8 waves 2Mx4N, per-wave 128 x NI*16; quarter-granular staging into just-freed
// regions; B rows nh-permuted. NEW: all fragment reads are opaque asm ds_read_b128
// so the ONLY vmem waits are the manual counted ones (vmcnt(6/5) at p3 -- queue
// never drains in steady state). Round 4's C++ reads let the compiler insert its
// own vmcnt(0) before every phase's LDS reads, which flattened all schedules to
// the same ~30% MfmaUtil.
template <typename OutT, int NI>
__global__ __launch_bounds__(512, 2) void k_gemm8p(const bf16* __restrict__ A,
                                                   const bf16* __restrict__ Bt,
                                                   OutT* __restrict__ C, int M, int N, int K) {
    constexpr int BN = NI * 64;
    __shared__ __align__(16) bf16 aL2[2 * 256 * 64];
    __shared__ __align__(16) bf16 bL2[2 * BN * 64];
    const int t    = threadIdx.x;
    const int lane = t & 63;
    const int w    = t >> 6;
    const int quad = lane >> 4;
    const int l16  = lane & 15;
    const int wr   = w >> 2;               // 0..1  (M)
    const int wc   = w & 3;                // 0..3  (N)

    // XCD swizzle (nwg = 256, divisible by 8)
    int bid = blockIdx.y * gridDim.x + blockIdx.x;
    int cpx = (gridDim.x * gridDim.y) >> 3;
    int sw  = (bid & 7) * cpx + (bid >> 3);
    int bx  = sw % gridDim.x, by = sw / gridDim.x;
    const int m0 = by * 256;
    const int n0 = bx * BN;

    f32x4 acc[8][NI] = {};

    auto stageA2 = [&](int kb, int dbuf, int itX, int itY) {
        const int k0 = kb << 6;
        #pragma unroll
        for (int u = 0; u < 2; ++u) {
            int it = u ? itY : itX;
            int ci = it * 512 + t;
            int r = ci >> 3, c = ci & 7;
            int cg = c ^ (r & 7);          // slot c of row r holds global chunk c^(r&7)
            gll16(A + (size_t)(m0 + r) * K + k0 + cg * 8, aL2 + dbuf * (256 * 64) + ci * 8);
        }
    };
    auto stageBh = [&](int kb, int dbuf, int nh) {
        const int k0 = kb << 6;
        #pragma unroll
        for (int j = 0; j < NI / 2; ++j) {
            int it = nh * (NI / 2) + j;
            int ci = it * 512 + t;
            int lr = ci >> 3, cs = ci & 7;
            int cg = cs ^ (lr & 7);
            int idx = lr - nh * (BN / 2);  // position within the nh half
            int wcc = idx / (NI * 8);
            int off = idx % (NI * 8);
            int g   = wcc * (NI * 16) + nh * (NI * 8) + off;   // global B row
            gll16(Bt + (size_t)(n0 + g) * K + k0 + cg * 8, bL2 + dbuf * (BN * 64) + ci * 8);
        }
    };

    // asm fragment loads (addresses identical to round 4's verified C++ reads)
    auto loadA = [&](const bf16* aL, int mh, bf16x8 (&af)[8]) {
        #pragma unroll
        for (int mi = 0; mi < 4; ++mi)
            #pragma unroll
            for (int kk = 0; kk < 2; ++kk) {
                int row = wr * 128 + (mh * 4 + mi) * 16 + l16;
                int ch  = (kk * 4 + quad) ^ (row & 7);
                dsr128(af[mi * 2 + kk], &aL[row * 64 + ch * 8]);
            }
    };
    auto loadB = [&](const bf16* bL, int nh, bf16x8 (&bfr)[NI]) {
        #pragma unroll
        for (int j = 0; j < NI / 2; ++j)
            #pragma unroll
            for (int kk = 0; kk < 2; ++kk) {
                int lr = nh * (BN / 2) + wc * (NI * 8) + j * 16 + l16;  // permuted row
                int ch = (kk * 4 + quad) ^ (lr & 7);
                dsr128(bfr[j * 2 + kk], &bL[lr * 64 + ch * 8]);
            }
    };
    auto mmac = [&](int mh, int nh, bf16x8 (&af)[8], bf16x8 (&bfr)[NI]) {
        __builtin_amdgcn_s_setprio(1);
        #pragma unroll
        for (int mi = 0; mi < 4; ++mi)
            #pragma unroll
            for (int j = 0; j < NI / 2; ++j)
                #pragma unroll
                for (int kk = 0; kk < 2; ++kk)
                    acc[mh * 4 + mi][nh * (NI / 2) + j] =
                        __builtin_amdgcn_mfma_f32_16x16x32_bf16(af[mi * 2 + kk], bfr[j * 2 + kk],
                                                                acc[mh * 4 + mi][nh * (NI / 2) + j], 0, 0, 0);
        __builtin_amdgcn_s_setprio(0);
    };

    const int NT = K >> 6;                 // 16

    auto tile = [&](int T, int bufc) {
        const bf16* aL = aL2 + bufc * (256 * 64);
        const bf16* bL = bL2 + bufc * (BN * 64);
        bf16x8 af[8], bfr[NI];
        // p0: (0,0); stage B-nh1 of T+1 into buf^1 (freed at T-1.p3)
        loadA(aL, 0, af); loadB(bL, 0, bfr);
        if (T + 1 < NT) stageBh(T + 1, bufc ^ 1, 1);
        bar(); lgkm0();
        mmac(0, 0, af, bfr);
        bar();
        // p1: (0,1); stage A-mh0 quarters of T+2 (freed at p0)
        loadB(bL, 1, bfr);
        if (T + 2 < NT) stageA2(T + 2, bufc, 0, 2);
        bar(); lgkm0();
        mmac(0, 1, af, bfr);
        bar();
        // p2: (1,0)
        loadA(aL, 1, af); loadB(bL, 0, bfr);
        bar(); lgkm0();
        mmac(1, 0, af, bfr);
        bar();
        // p3: (1,1); stage A-mh1 + B-nh0 of T+2 (freed at p2); ONE counted wait per
        // tile: allow T+2's 6 (NI=4) / 5 (NI=2) loads to remain in flight -> tile
        // T+1 fully staged, queue never drains.
        loadB(bL, 1, bfr);
        if (T + 2 < NT) { stageA2(T + 2, bufc, 1, 3); stageBh(T + 2, bufc, 0); }
        bar(); lgkm0();
        mmac(1, 1, af, bfr);
        if (T + 2 < NT) { if constexpr (NI == 4) vm_wait6(); else vm_wait5(); }
        else vm_wait0();
        bar();
    };

    // prologue: tile 0 full; tile 1 all but B-nh1 (staged at tile0.p0)
    stageA2(0, 0, 0, 2); stageA2(0, 0, 1, 3); stageBh(0, 0, 0); stageBh(0, 0, 1);
    stageA2(1, 1, 0, 2); stageA2(1, 1, 1, 3); stageBh(1, 1, 0);
    if constexpr (NI == 4) vm_wait6(); else vm_wait5();   // tile 0 landed; tile 1 in flight
    bar();

    for (int T = 0; T < NT; T += 2) {      // literal buffer index at both call sites
        tile(T, 0);
        tile(T + 1, 1);
    }

    #pragma unroll
    for (int mi = 0; mi < 8; ++mi)
        #pragma unroll
        for (int ni = 0; ni < NI; ++ni)
            #pragma unroll
            for (int r = 0; r < 4; ++r) {
                int row = m0 + wr * 128 + mi * 16 + quad * 4 + r;   // C/D: row = quad*4+reg
                int col = n0 + wc * (NI * 16) + ni * 16 + l16;      //      col = lane&15
                C[(size_t)row * N + col] = (OutT)acc[mi][ni][r];
            }
}

// ---------------- fused prep2: RoPE scatter (blocks 0..8191) + V transpose ----------------
__global__ void k_prep2(const bf16* __restrict__ qkv, const float* __restrict__ cosg,
                        const float* __restrict__ sing, bf16* __restrict__ qd,
                        bf16* __restrict__ kd, bf16* __restrict__ vt) {
    __shared__ __align__(16) bf16 tile[64 * 72];
    int bid = blockIdx.x;
    int t = threadIdx.x;
    if (bid < 8192) {                       // RoPE: 192 active lanes/token
        if (t < 192) {
            int token = bid;
            int b = token >> 10, s = token & 1023;
            int hh = t >> 3, i8 = t & 7;
            float4 c4 = *(const float4*)&cosg[s * 32 + i8 * 4];
            float4 s4 = *(const float4*)&sing[s * 32 + i8 * 4];
            int srcBase, dstBase;
            bf16* dst;
            float sf;
            if (hh < 16) {
                srcBase = token * 2048 + hh * 64;
                dstBase = ((b * NH_ + hh) * S_ + s) * 64;
                dst = qd;
                sf = 0.180336879f;          // 0.125 * log2(e) folded into Q
            } else {
                int h = hh - 16;
                srcBase = token * 2048 + 1024 + h * 64;
                dstBase = ((b * NKV_ + h) * S_ + s) * 64;
                dst = kd;
                sf = 1.0f;
            }
            bf16x8 v = *(const bf16x8*)&qkv[srcBase + i8 * 8];
            const float cc[4] = { c4.x, c4.y, c4.z, c4.w };
            const float ss[4] = { s4.x, s4.y, s4.z, s4.w };
            bf16x8 o;
            #pragma unroll
            for (int j = 0; j < 4; ++j) {
                float e  = (float)v[2 * j];
                float od = (float)v[2 * j + 1];
                o[2 * j]     = (bf16)(sf * (e * cc[j] - od * ss[j]));
                o[2 * j + 1] = (bf16)(sf * (e * ss[j] + od * cc[j]));
            }
            *(bf16x8*)&dst[dstBase + i8 * 8] = o;
        }
        return;
    }
    int b2 = bid - 8192;                    // 0..1023 vtrans tiles
    int st = b2 & 15;
    int h  = (b2 >> 4) & 7;
    int b  = b2 >> 7;
    int s0 = st * 64;
    #pragma unroll
    for (int it = 0; it < 2; ++it) {
        int ci = it * 256 + t;
        int r = ci >> 3, c = ci & 7;           // r = s, c = d-chunk
        *(uint4*)&tile[r * 72 + c * 8] =
            *(const uint4*)&qkv[(size_t)(b * S_ + s0 + r) * 2048 + 1536 + h * 64 + c * 8];
    }
    __syncthreads();
    #pragma unroll
    for (int it = 0; it < 2; ++it) {
        int ci = it * 256 + t;
        int d = ci >> 3, sc = ci & 7;
        int g = sc >> 2, q4 = sc & 3;          // internal chunk -> (32-group, quad)
        bf16x8 v;
        #pragma unroll
        for (int j = 0; j < 8; ++j) {
            int s_ext = g * 32 + q4 * 4 + (j & 3) + 16 * (j >> 2);
            v[j] = tile[s_ext * 72 + d];
        }
        *(bf16x8*)&vt[(size_t)((b * NKV_ + h) * 64 + d) * S_ + s0 + sc * 8] = v;
    }
}

// ---------------- flash attention, asm ds_read edition ----------------
// Math/addressing identical to rounds 2-4 (verified). NEW: asm ds_read K/V frags
// (no compiler vmcnt drains), {bar; stage(u+1); vmcnt(4); bar; compute} schedule:
// stage(u)'s loads land under unit u-1's compute so vmcnt(4) is near-free and the
// vmem queue keeps next unit's 4 loads in flight through each unit's compute.
// V reads are issued before the softmax VALU so ds_read latency hides under exp2.
__global__ __launch_bounds__(256, 4) void k_attn(const bf16* __restrict__ q, const bf16* __restrict__ k,
                                                 const bf16* __restrict__ vt, bf16* __restrict__ out) {
    __shared__ __align__(16) bf16 kt[2 * 64 * 64];
    __shared__ __align__(16) bf16 vtt[2 * 64 * 64];
    int bid = blockIdx.x;
    int qt = 15 - (bid >> 7);               // big q-tiles first
    int combo = bid & 127;
    int b = combo >> 4, h = combo & 15;
    int hkv = h >> 1;                       // jnp.repeat: q-head h -> kv head h/2
    int t = threadIdx.x;
    int w = t >> 6, lane = t & 63, quad = lane >> 4, l16 = lane & 15;

    const bf16* qh = q + (size_t)(b * NH_ + h) * S_ * 64;
    int qw = qt * 64 + w * 16;
    const bf16* qb = qh + (size_t)(qw + l16) * 64;
    bf16x8 qf0 = *(const bf16x8*)(qb + quad * 8);
    bf16x8 qf1 = *(const bf16x8*)(qb + 32 + quad * 8);

    const bf16* kg = k  + (size_t)(b * NKV_ + hkv) * S_ * 64;
    const bf16* vg = vt + (size_t)(b * NKV_ + hkv) * 64 * S_;

    const int sr0 = t >> 3;                 // staging row 0..31 (+32 for it=1)
    const int cs  = t & 7;                  // staging swizzled chunk slot

    auto stage = [&](int u, int buf) {
        int k0 = u * 64;
        #pragma unroll
        for (int it = 0; it < 2; ++it) {
            int r  = sr0 + it * 32;
            int cg = cs ^ (r & 7);          // slot cs holds global chunk cs^(r&7)
            int ci = it * 256 + t;
            gll16(kg + (size_t)(k0 + r) * 64 + cg * 8, kt  + buf * 4096 + ci * 8);
            gll16(vg + (size_t)r * S_ + k0 + cg * 8,   vtt + buf * 4096 + ci * 8);
        }
    };

    const bf16 one = (bf16)1.0f;
    const bf16x8 vones = { one, one, one, one, one, one, one, one };

    f32x4 o[4] = {};        // PV C-layout: row q=quad*4+r, col d=dc*16+l16
    f32x4 ol = {};          // ones-column: ol[r] = row-sum of P for q=quad*4+r
    const int klim = ((qw + l16) & ~7) + 8; // block-causal, BLK=8

    auto unit = [&](const bf16* ktb, const bf16* vtb, int k0, bool diag) {
        // QK^T: 8 asm K reads -> lgkm -> MFMA
        bf16x8 af[8];
        #pragma unroll
        for (int kk = 0; kk < 2; ++kk)
            #pragma unroll
            for (int f = 0; f < 4; ++f) {
                int row = f * 16 + l16;
                int ch  = (kk * 4 + quad) ^ (row & 7);
                dsr128(af[kk * 4 + f], &ktb[row * 64 + ch * 8]);
            }
        lgkm0();
        f32x4 sc[4] = {};
        __builtin_amdgcn_s_setprio(1);
        #pragma unroll
        for (int kk = 0; kk < 2; ++kk)
            #pragma unroll
            for (int f = 0; f < 4; ++f)
                sc[f] = __builtin_amdgcn_mfma_f32_16x16x32_bf16(af[kk * 4 + f], kk ? qf1 : qf0, sc[f], 0, 0, 0);
        __builtin_amdgcn_s_setprio(0);

        // Issue V reads NOW -- latency hides under the softmax VALU below
        bf16x8 vbf[8];
        #pragma unroll
        for (int dc = 0; dc < 4; ++dc)
            #pragma unroll
            for (int kk = 0; kk < 2; ++kk) {
                int row = dc * 16 + l16;
                int ch  = (kk * 4 + quad) ^ (row & 7);
                dsr128(vbf[dc * 2 + kk], &vtb[row * 64 + ch * 8]);
            }

        // p = exp2(sc) directly (Q pre-scaled); masked -> 0. No running max.
        float p[4][4];
        #pragma unroll
        for (int f = 0; f < 4; ++f)
            #pragma unroll
            for (int r = 0; r < 4; ++r) {
                float pv = __builtin_amdgcn_exp2f(sc[f][r]);
                if (diag && (k0 + f * 16 + quad * 4 + r >= klim)) pv = 0.f;
                p[f][r] = pv;
            }
        bf16x8 pa0, pa1;
        #pragma unroll
        for (int j = 0; j < 4; ++j) {
            pa0[j]     = (bf16)p[0][j];
            pa0[j + 4] = (bf16)p[1][j];
            pa1[j]     = (bf16)p[2][j];
            pa1[j + 4] = (bf16)p[3][j];
        }
        ol = __builtin_amdgcn_mfma_f32_16x16x32_bf16(pa0, vones, ol, 0, 0, 0);
        ol = __builtin_amdgcn_mfma_f32_16x16x32_bf16(pa1, vones, ol, 0, 0, 0);

        lgkm0();
        __builtin_amdgcn_s_setprio(1);
        #pragma unroll
        for (int dc = 0; dc < 4; ++dc)
            #pragma unroll
            for (int kk = 0; kk < 2; ++kk)
                o[dc] = __builtin_amdgcn_mfma_f32_16x16x32_bf16(kk ? pa1 : pa0, vbf[dc * 2 + kk], o[dc], 0, 0, 0);
        __builtin_amdgcn_s_setprio(0);
    };

    const int NU = qt + 1;
    stage(0, 0);
    // Pin the compiler's Q-load wait HERE (single vmcnt before the loop), not
    // inside the loop body.
    asm volatile("" :: "v"(qf0), "v"(qf1));

    int u = 0;
    for (; u + 2 <= NU; u += 2) {
        bar();                              // close readers of buf1 (unit u-1)
        stage(u + 1, 1);
        vm_wait4();                         // stage(u) landed; stage(u+1) in flight
        bar();                              // publish buf0
        unit(kt, vtt, u * 64, false);       // u <= NU-2: never diagonal
        bar();                              // close readers of buf0
        bool hn = (u + 2 < NU);
        if (hn) { stage(u + 2, 0); vm_wait4(); } else vm_wait0();
        bar();                              // publish buf1
        unit(kt + 4096, vtt + 4096, (u + 1) * 64, (u + 1) == NU - 1);
    }
    if (u < NU) {                           // odd-NU tail: diagonal unit, buf0
        bar();
        vm_wait0();
        bar();
        unit(kt, vtt, u * 64, true);
    }

    // epilogue
    #pragma unroll
    for (int r = 0; r < 4; ++r) {
        float invl = 1.0f / ol[r];
        #pragma unroll
        for (int dc = 0; dc < 4; ++dc) {
            int row = qw + quad * 4 + r;
            int col = h * 64 + dc * 16 + l16;
            out[(size_t)(b * S_ + row) * 1024 + col] = (bf16)(o[dc][r] * invl);
        }
    }
}

// ---------------- launch ----------------
extern "C" void kernel_launch(void* const* d_in, const int* in_sizes, int n_in,
                              void* d_out, int out_size, void* d_ws, size_t ws_size,
                              hipStream_t stream) {
    const float* x  = (const float*)d_in[0];
    const float* wq = (const float*)d_in[1];
    const float* wk = (const float*)d_in[2];
    const float* wv = (const float*)d_in[3];
    const float* wo = (const float*)d_in[4];
    const float* fc = (const float*)d_in[5];
    const float* fs = (const float*)d_in[6];
    (void)in_sizes; (void)n_in; (void)out_size; (void)ws_size;

    char* ws = (char*)d_ws;
    bf16* xb    = (bf16*)(ws);                          // 16 MB, reused as q after GEMM1
    bf16* wqkvT = (bf16*)(ws + (16u << 20));            //  4 MB  [2048][1024]
    bf16* woT   = (bf16*)(ws + (20u << 20));            //  2 MB  [1024][1024]
    bf16* qkvb  = (bf16*)(ws + (22u << 20));            // 32 MB  [8192][2048], reused as attn out
    bf16* kb    = (bf16*)(ws + (54u << 20));            //  8 MB  [8][8][1024][64]
    bf16* vtb   = (bf16*)(ws + (62u << 20));            //  8 MB  [8][8][64][1024]  (70 MB total)
    bf16* qb    = xb;
    bf16* attnb = qkvb;

    k_prep1<<<dim3(8960), dim3(256), 0, stream>>>(x, wq, wk, wv, wo, xb, wqkvT, woT);

    // GEMM1: [8192,1024] x [2048,1024]^T -> 256x256 tiles, grid 8x32 = 256 wgs (1/CU)
    k_gemm8p<bf16, 4><<<dim3(8, 32), dim3(512), 0, stream>>>(xb, wqkvT, qkvb, M_, 2048, 1024);

    k_prep2<<<dim3(9216), dim3(256), 0, stream>>>(qkvb, fc, fs, qb, kb, vtb);

    // attn: per-q-tile blocks, 2048 wgs, big tiles first
    k_attn<<<dim3(2048), dim3(256), 0, stream>>>(qb, kb, vtb, attnb);

    // GEMM2: [8192,1024] x [1024,1024]^T -> 256x128 tiles, grid 8x32 = 256 wgs (1/CU)
    k_gemm8p<float, 2><<<dim3(8, 32), dim3(512), 0, stream>>>(attnb, woT, (float*)d_out, M_, 1024, 1024);
}